// Round 2
// baseline (547.138 us; speedup 1.0000x reference)
//
#include <hip/hip_runtime.h>

#define NIMG 512
#define H 64
#define W 64
#define C 32
#define HW (H * W)

typedef _Float16 half8 __attribute__((ext_vector_type(8)));
typedef _Float16 half4v __attribute__((ext_vector_type(4)));

__device__ __forceinline__ int iclamp(int v, int lo, int hi) {
    return v < lo ? lo : (v > hi ? hi : v);
}

__device__ __forceinline__ half8 splat8(_Float16 x) {
    half8 v = {x, x, x, x, x, x, x, x};
    return v;
}

// ---------------------------------------------------------------------------
// Pass 1: pack/transpose X (N, HW, 32) fp32 -> Xh (N, 4, HW, 8) fp16.
// One thread = one source pixel (all 32 channels): reads a full 128 B line
// (dense 8 KiB per wave), writes 4x 16 B octet streams (each dense 1 KiB per
// wave). Zero line amplification on either side.
// XCD swizzle: image n lands on XCD n/64 so pass 2 (same mapping) finds its
// slice in that XCD's L2/L3.
// ---------------------------------------------------------------------------
__global__ __launch_bounds__(256) void stn_pack_kernel(
    const float* __restrict__ X, _Float16* __restrict__ Xh)
{
    const int b     = blockIdx.x;          // 8192 blocks
    const int xcd   = b & 7;
    const int sub   = b >> 3;              // 0..1023
    const int n     = xcd * 64 + (sub >> 4);
    const int chunk = sub & 15;            // 16 chunks of 256 px per image
    const int p     = chunk * 256 + threadIdx.x;

    const float* src = X + ((size_t)n * HW + p) * C;
    float v[32];
#pragma unroll
    for (int i = 0; i < 8; ++i)
        *(float4*)&v[i * 4] = ((const float4*)src)[i];

    _Float16* dst = Xh + (size_t)n * (4 * HW * 8) + (size_t)p * 8;
#pragma unroll
    for (int o = 0; o < 4; ++o) {
        half8 hv;
#pragma unroll
        for (int k = 0; k < 8; ++k) hv[k] = (_Float16)v[o * 8 + k];
        *(half8*)(dst + (size_t)o * (HW * 8)) = hv;
    }
}

// ---------------------------------------------------------------------------
// Pass 2: gather. One thread = one output pixel, all 32 channels.
// In octet-major fp16, each corner is ONE contiguous 16 B load; x-adjacent
// pixels are 16 B apart so neighboring cols' corners share 128 B lines
// (amplification ~1 vs 4-8x in the channel-split LDS scheme). No LDS, no
// barrier; fp64 coordinate math (identical to the passing kernel) done once
// per pixel and shared across the 4 octets; pk-fp16 blend (verified path).
// ---------------------------------------------------------------------------
__global__ __launch_bounds__(256) void stn_gather_kernel(
    const _Float16* __restrict__ Xh,
    const float* __restrict__ theta,
    float* __restrict__ out)
{
    const int b     = blockIdx.x;          // 8192 blocks
    const int xcd   = b & 7;
    const int sub   = b >> 3;
    const int n     = xcd * 64 + (sub >> 4);
    const int chunk = sub & 15;
    const int p     = chunk * 256 + threadIdx.x;
    const int row   = p >> 6;
    const int col   = p & 63;

    // Per-image affine params (uniform across the block; scalar loads).
    const float* th = theta + n * 6;
    const double a00 = (double)th[0], a01 = (double)th[1], a02 = (double)th[2];
    const double a10 = (double)th[3], a11 = (double)th[4], a12 = (double)th[5];

    // np.linspace(-1, 1, 64) semantics: step = 2/63, endpoint exact 1.0.
    const double step = 2.0 / 63.0;
    const double xj = (col == W - 1) ? 1.0 : ((double)col * step - 1.0);
    const double yi = (row == H - 1) ? 1.0 : ((double)row * step - 1.0);

    const double gs0 = (a00 * xj + a01 * yi) + a02;
    const double gs1 = (a10 * xj + a11 * yi) + a12;
    const double gx = (double)W * (gs0 + 1.0) * 0.5;
    const double gy = (double)H * (gs1 + 1.0) * 0.5;

    double fx = floor(gx);
    double fy = floor(gy);
    fx = fmin(fmax(fx, -1.0e6), 1.0e6);  // defensive: keep int cast defined
    fy = fmin(fmax(fy, -1.0e6), 1.0e6);
    const int x0i = (int)fx;
    const int y0i = (int)fy;

    const int X0 = iclamp(x0i,     0, W - 1);
    const int X1 = iclamp(x0i + 1, 0, W - 1);
    const int Y0 = iclamp(y0i,     0, H - 1);
    const int Y1 = iclamp(y0i + 1, 0, H - 1);

    float wax = (float)((double)X1 - gx);
    float wbx = (float)(gx - (double)X0);
    float way = (float)((double)Y1 - gy);
    float wby = (float)(gy - (double)Y0);

    // Clamped axis => corners identical, exact weight sum 0 (reference's own
    // fp32 pairing cancels to <=1e-4): emit exactly 0 and keep all weights
    // in [0,1] so the fp16 blend stays well-conditioned.
    if (X0 == X1) { wax = 0.0f; wbx = 0.0f; }
    if (Y0 == Y1) { way = 0.0f; wby = 0.0f; }

    const half8 vway = splat8((_Float16)way);
    const half8 vwby = splat8((_Float16)wby);
    const half8 vwax = splat8((_Float16)wax);
    const half8 vwbx = splat8((_Float16)wbx);

    const _Float16* base = Xh + (size_t)n * (4 * HW * 8);
    const int iA = (Y0 * W + X0) * 8;
    const int iB = (Y1 * W + X0) * 8;
    const int iC = (Y0 * W + X1) * 8;
    const int iD = (Y1 * W + X1) * 8;

    // Issue all 16 gathers up front (independent, 16 B each) for latency
    // hiding; static indexing keeps them in registers.
    half8 Av[4], Bv[4], Cv[4], Dv[4];
#pragma unroll
    for (int o = 0; o < 4; ++o) {
        const _Float16* bo = base + (size_t)o * (HW * 8);
        Av[o] = *(const half8*)(bo + iA);
        Bv[o] = *(const half8*)(bo + iB);
        Cv[o] = *(const half8*)(bo + iC);
        Dv[o] = *(const half8*)(bo + iD);
    }

    float* po = out + ((size_t)n * HW + p) * C;
#pragma unroll
    for (int o = 0; o < 4; ++o) {
        const half8 left  = Av[o] * vway + Bv[o] * vwby;
        const half8 right = Cv[o] * vway + Dv[o] * vwby;
        const half8 res   = left * vwax + right * vwbx;
        float rf[8];
#pragma unroll
        for (int k = 0; k < 8; ++k) rf[k] = (float)res[k];
        ((float4*)po)[o * 2]     = make_float4(rf[0], rf[1], rf[2], rf[3]);
        ((float4*)po)[o * 2 + 1] = make_float4(rf[4], rf[5], rf[6], rf[7]);
    }
}

// ---------------------------------------------------------------------------
// Fallback (ws too small): the verified round-1 single-pass LDS kernel.
// ---------------------------------------------------------------------------
#define TPB 512
__global__ __launch_bounds__(TPB) void stn_bilinear_lds_kernel(
    const float* __restrict__ X,
    const float* __restrict__ theta,
    float* __restrict__ out)
{
    __shared__ _Float16 s[HW * 8];

    const int b   = blockIdx.x;
    const int xcd = b & 7;
    const int sb  = b >> 3;
    const int oct = sb & 3;
    const int n   = xcd + ((sb >> 2) << 3);
    const int tid = threadIdx.x;

    const float* th = theta + n * 6;
    const double a00 = (double)th[0], a01 = (double)th[1], a02 = (double)th[2];
    const double a10 = (double)th[3], a11 = (double)th[4], a12 = (double)th[5];

    const float* img = X + (size_t)n * (HW * C) + oct * 8;

    for (int it = tid; it < HW * 2; it += TPB) {
        const int p  = it >> 1;
        const int hf = it & 1;
        const float4 v = *(const float4*)(img + (size_t)p * C + hf * 4);
        half4v hv = {(_Float16)v.x, (_Float16)v.y, (_Float16)v.z, (_Float16)v.w};
        *(half4v*)&s[p * 8 + hf * 4] = hv;
    }

    __syncthreads();

    const double step = 2.0 / 63.0;
    float* outb = out + (size_t)n * (HW * C) + oct * 8;

    for (int it = tid; it < HW; it += TPB) {
        const int row = it >> 6;
        const int col = it & 63;

        const double xj = (col == W - 1) ? 1.0 : ((double)col * step - 1.0);
        const double yi = (row == H - 1) ? 1.0 : ((double)row * step - 1.0);

        const double gs0 = (a00 * xj + a01 * yi) + a02;
        const double gs1 = (a10 * xj + a11 * yi) + a12;
        const double gx = (double)W * (gs0 + 1.0) * 0.5;
        const double gy = (double)H * (gs1 + 1.0) * 0.5;

        double fx = floor(gx);
        double fy = floor(gy);
        fx = fmin(fmax(fx, -1.0e6), 1.0e6);
        fy = fmin(fmax(fy, -1.0e6), 1.0e6);
        const int x0i = (int)fx;
        const int y0i = (int)fy;

        const int X0 = iclamp(x0i,     0, W - 1);
        const int X1 = iclamp(x0i + 1, 0, W - 1);
        const int Y0 = iclamp(y0i,     0, H - 1);
        const int Y1 = iclamp(y0i + 1, 0, H - 1);

        float wax = (float)((double)X1 - gx);
        float wbx = (float)(gx - (double)X0);
        float way = (float)((double)Y1 - gy);
        float wby = (float)(gy - (double)Y0);

        if (X0 == X1) { wax = 0.0f; wbx = 0.0f; }
        if (Y0 == Y1) { way = 0.0f; wby = 0.0f; }

        const half8 A  = *(const half8*)&s[(Y0 * W + X0) * 8];
        const half8 Bv = *(const half8*)&s[(Y1 * W + X0) * 8];
        const half8 Cv = *(const half8*)&s[(Y0 * W + X1) * 8];
        const half8 Dv = *(const half8*)&s[(Y1 * W + X1) * 8];

        const half8 vway = splat8((_Float16)way);
        const half8 vwby = splat8((_Float16)wby);
        const half8 vwax = splat8((_Float16)wax);
        const half8 vwbx = splat8((_Float16)wbx);

        const half8 left  = A  * vway + Bv * vwby;
        const half8 right = Cv * vway + Dv * vwby;
        const half8 res   = left * vwax + right * vwbx;

        float rf[8];
#pragma unroll
        for (int k = 0; k < 8; ++k) rf[k] = (float)res[k];

        float* po = outb + (size_t)it * C;
        *(float4*)(po)     = make_float4(rf[0], rf[1], rf[2], rf[3]);
        *(float4*)(po + 4) = make_float4(rf[4], rf[5], rf[6], rf[7]);
    }
}

extern "C" void kernel_launch(void* const* d_in, const int* in_sizes, int n_in,
                              void* d_out, int out_size, void* d_ws, size_t ws_size,
                              hipStream_t stream) {
    const float* X     = (const float*)d_in[0];
    const float* theta = (const float*)d_in[1];
    float* out         = (float*)d_out;

    const size_t need = (size_t)NIMG * 4 * HW * 8 * sizeof(_Float16);  // 128 MiB

    if (d_ws != nullptr && ws_size >= need) {
        _Float16* Xh = (_Float16*)d_ws;
        const int blocks = NIMG * HW / 256;  // 8192
        hipLaunchKernelGGL(stn_pack_kernel, dim3(blocks), dim3(256), 0, stream,
                           X, Xh);
        hipLaunchKernelGGL(stn_gather_kernel, dim3(blocks), dim3(256), 0, stream,
                           Xh, theta, out);
    } else {
        const int blocks = NIMG * 4;
        hipLaunchKernelGGL(stn_bilinear_lds_kernel, dim3(blocks), dim3(TPB), 0,
                           stream, X, theta, out);
    }
}

// Round 4
// 425.725 us; speedup vs baseline: 1.2852x; 1.2852x over previous
//
#include <hip/hip_runtime.h>

#define NIMG 512
#define H 64
#define W 64
#define C 32
#define HW (H * W)

typedef float f32x4 __attribute__((ext_vector_type(4)));

__device__ __forceinline__ int iclamp(int v, int lo, int hi) {
    return v < lo ? lo : (v > hi ? hi : v);
}

// Round-0 proven structure, de-fatted:
//  - one block = 2 output rows (512 threads); 4 threads/pixel, 8 ch each.
//    The 4-lane quad covers each 128 B corner line with 2 coalesced 64 B
//    transactions (best scatter granularity measured so far).
//  - fp32 coordinate math (reference is JAX fp32; bilinear is continuous in
//    gx/gy so ulp-level floor disagreements give ulp-level output changes).
//    Shorter dependency chain before the corner loads issue.
//  - pure fp32 data path (no fp16 quantization).
//  - nontemporal stores: output has zero reuse; keep X resident in L2/L3.
//  - XCD-locality swizzle: blockIdx%8 assumed to round-robin XCDs; each XCD
//    gets a contiguous slab of 64 images so each 512 KiB source image stays
//    resident in that XCD's 4 MiB L2 while its 32 row-pair blocks run.
//    Heuristic only; correctness independent of the mapping.
__global__ __launch_bounds__(512) void stn_bilinear_f32_kernel(
    const float* __restrict__ X,       // (N, H, W, C) fp32
    const float* __restrict__ theta,   // (N, 6) fp32
    float* __restrict__ out)           // (N, H, W, C) fp32
{
    const int b    = blockIdx.x;            // 16384 blocks
    const int xcd  = b & 7;
    const int sub  = b >> 3;                // 0..2047
    const int n    = xcd * 64 + (sub >> 5); // image 0..511
    const int t    = threadIdx.x;
    const int row  = ((sub & 31) << 1) | (t >> 8);  // output row
    const int col  = (t >> 2) & 63;                 // output col
    const int quad = t & 3;                         // channel group of 8

    // Per-image affine params (uniform across the block; scalar loads).
    const float* th = theta + n * 6;
    const float a00 = th[0], a01 = th[1], a02 = th[2];
    const float a10 = th[3], a11 = th[4], a12 = th[5];

    // linspace(-1, 1, 64): step = 2/63, endpoint forced to exactly 1.0.
    const float step = 2.0f / 63.0f;
    const float xj = (col == W - 1) ? 1.0f : ((float)col * step - 1.0f);
    const float yi = (row == H - 1) ? 1.0f : ((float)row * step - 1.0f);

    const float gs0 = a00 * xj + a01 * yi + a02;
    const float gs1 = a10 * xj + a11 * yi + a12;
    const float gx = (float)W * (gs0 + 1.0f) * 0.5f;
    const float gy = (float)H * (gs1 + 1.0f) * 0.5f;

    float fx = floorf(gx);
    float fy = floorf(gy);
    fx = fminf(fmaxf(fx, -1.0e6f), 1.0e6f);  // defensive: keep int cast defined
    fy = fminf(fmaxf(fy, -1.0e6f), 1.0e6f);
    const int x0i = (int)fx;
    const int y0i = (int)fy;

    const int X0 = iclamp(x0i,     0, W - 1);
    const int X1 = iclamp(x0i + 1, 0, W - 1);
    const int Y0 = iclamp(y0i,     0, H - 1);
    const int Y1 = iclamp(y0i + 1, 0, H - 1);

    // Weight factors from CLIPPED corners (matches reference). When an axis
    // is clamped (X0==X1), (X1-gx) and (gx-X0) are exact fp32 negations, so
    // the two corner contributions cancel exactly — same cancellation the
    // fp32 reference performs.
    const float dwax = (float)X1 - gx;
    const float dwbx = gx - (float)X0;
    const float dway = (float)Y1 - gy;
    const float dwby = gy - (float)Y0;

    const float* img = X + (size_t)n * (HW * C);
    const int cb = quad * 8;  // channel base

    const f32x4* pa = (const f32x4*)(img + (Y0 * W + X0) * C + cb);
    const f32x4* pb = (const f32x4*)(img + (Y1 * W + X0) * C + cb);
    const f32x4* pc = (const f32x4*)(img + (Y0 * W + X1) * C + cb);
    const f32x4* pd = (const f32x4*)(img + (Y1 * W + X1) * C + cb);

    // 8 independent 16 B loads — issue all up front for latency hiding.
    float A[8], B[8], Cv[8], D[8];
    *(f32x4*)&A[0]  = pa[0];  *(f32x4*)&A[4]  = pa[1];
    *(f32x4*)&B[0]  = pb[0];  *(f32x4*)&B[4]  = pb[1];
    *(f32x4*)&Cv[0] = pc[0];  *(f32x4*)&Cv[4] = pc[1];
    *(f32x4*)&D[0]  = pd[0];  *(f32x4*)&D[4]  = pd[1];

    float r[8];
#pragma unroll
    for (int k = 0; k < 8; ++k) {
        r[k] = dwax * (dway * A[k] + dwby * B[k])
             + dwbx * (dway * Cv[k] + dwby * D[k]);
    }

    float* po = out + ((size_t)n * HW + (size_t)(row * W + col)) * C + cb;
    __builtin_nontemporal_store(*(const f32x4*)&r[0], (f32x4*)po);
    __builtin_nontemporal_store(*(const f32x4*)&r[4], (f32x4*)(po + 4));
}

extern "C" void kernel_launch(void* const* d_in, const int* in_sizes, int n_in,
                              void* d_out, int out_size, void* d_ws, size_t ws_size,
                              hipStream_t stream) {
    const float* X     = (const float*)d_in[0];
    const float* theta = (const float*)d_in[1];
    float* out         = (float*)d_out;

    const int blocks = NIMG * H / 2;  // 16384 blocks, 2 output rows each
    hipLaunchKernelGGL(stn_bilinear_f32_kernel, dim3(blocks), dim3(512), 0,
                       stream, X, theta, out);
}